// Round 11
// baseline (411.425 us; speedup 1.0000x reference)
//
#include <hip/hip_runtime.h>
#include <hip/hip_bf16.h>
#include <cstdint>
#include <cstddef>

#define B 4
#define NN 32768
#define NE 262144
#define CV 16
#define CE 16
#define HID 64
#define CM 48   // 2*CV + CE

using frag  = __attribute__((ext_vector_type(8))) short;
using f32x4 = __attribute__((ext_vector_type(4))) float;

__device__ __forceinline__ float fast_tanh(float x) {
    float e = __expf(2.0f * x);
    return 1.0f - 2.0f / (e + 1.0f);
}

__device__ __forceinline__ unsigned short f2bf(float x) {
    union { float f; unsigned u; } v; v.f = x;
    unsigned r = (v.u + 0x7FFFu + ((v.u >> 16) & 1u)) >> 16;
    return (unsigned short)r;
}

__device__ __forceinline__ float bf2f(unsigned short x) {
    union { unsigned u; float f; } v; v.u = ((unsigned)x) << 16;
    return v.f;
}

__device__ __forceinline__ unsigned pk2bf(float lo, float hi) {
    union { __hip_bfloat162 h; unsigned u; } v;
    v.h = __float22bfloat162_rn(make_float2(lo, hi));
    return v.u;
}

// wave-private swizzled LDS offset: 128 B row stride; XOR byte bits 4..6 with row&7
__device__ __forceinline__ unsigned swo(int row, int byte_off) {
    return (unsigned)((row << 7) + (byte_off ^ ((row & 7) << 4)));
}

__device__ __forceinline__ void acc8(float* a, uint4 v) {
    a[0] += bf2f((unsigned short)(v.x & 0xFFFFu));
    a[1] += bf2f((unsigned short)(v.x >> 16));
    a[2] += bf2f((unsigned short)(v.y & 0xFFFFu));
    a[3] += bf2f((unsigned short)(v.y >> 16));
    a[4] += bf2f((unsigned short)(v.z & 0xFFFFu));
    a[5] += bf2f((unsigned short)(v.z >> 16));
    a[6] += bf2f((unsigned short)(v.w & 0xFFFFu));
    a[7] += bf2f((unsigned short)(v.w >> 16));
}

// ------- counts + rank + prepack + nv16, with LAST-BLOCK fused prefix scan -------------
// After all blocks' atomics are fenced, the last block to finish (done-ticket) runs the
// 32K-bin exclusive scan for both a and b (re-reads cnt L2-hot). No grid-wide spin.
__global__ __launch_bounds__(256) void count_kernel(
    const int* __restrict__ ca, const int* __restrict__ cb,
    int* __restrict__ cnt_a, int* __restrict__ cnt_b,
    int* __restrict__ rank_a, int* __restrict__ rank_b,
    int* __restrict__ start_a, int* __restrict__ start_b,
    int* __restrict__ done,
    const float* __restrict__ Wm1, const float* __restrict__ bm1,
    const float* __restrict__ Wm2,
    const float* __restrict__ Wu1, const float* __restrict__ bu1,
    const float* __restrict__ Wu2,
    const float* __restrict__ node_vals,
    unsigned short* __restrict__ pW1, unsigned short* __restrict__ pW2,
    unsigned short* __restrict__ pWu1, unsigned short* __restrict__ pWu2,
    unsigned short* __restrict__ nv16)
{
    int i = blockIdx.x * 256 + threadIdx.x;
    rank_a[i] = atomicAdd(&cnt_a[ca[i]], 1);
    rank_b[i] = atomicAdd(&cnt_b[cb[i]], 1);

    {
        int x0 = i * 8;
        const float4* src = (const float4*)(node_vals + x0);
        float4 v0 = src[0], v1 = src[1];
        uint4 o;
        o.x = pk2bf(v0.x, v0.y); o.y = pk2bf(v0.z, v0.w);
        o.z = pk2bf(v1.x, v1.y); o.w = pk2bf(v1.z, v1.w);
        *(uint4*)(nv16 + x0) = o;
    }

    if (blockIdx.x == 0) {
        for (int x = threadIdx.x; x < 4 * 2 * 64 * 8; x += 256) {
            int j = x & 7, lane = (x >> 3) & 63, ks = (x >> 9) & 1, mt = x >> 10;
            int m = mt * 16 + (lane & 15);
            int k = ks * 32 + (lane >> 4) * 8 + j;
            float w = (k < 48) ? Wm1[k * 64 + m] : (k == 48 ? bm1[m] : 0.0f);
            pW1[x] = f2bf(w);
        }
    } else if (blockIdx.x == 1) {
        for (int x = threadIdx.x; x < 3 * 2 * 64 * 8; x += 256) {
            int j = x & 7, lane = (x >> 3) & 63, ks = (x >> 9) & 1, mt = x >> 10;
            int m = mt * 16 + (lane & 15);
            int k = ks * 32 + (lane >> 4) * 8 + j;
            pW2[x] = f2bf(Wm2[k * 48 + m]);
        }
    } else if (blockIdx.x == 2) {
        for (int x = threadIdx.x; x < 4 * 2 * 64 * 8; x += 256) {
            int j = x & 7, lane = (x >> 3) & 63, ks = (x >> 9) & 1, mt = x >> 10;
            int m = mt * 16 + (lane & 15);
            int k = ks * 32 + (lane >> 4) * 8 + j;
            float w = (k < 48) ? Wu1[k * 64 + m] : (k == 48 ? bu1[m] : 0.0f);
            pWu1[x] = f2bf(w);
        }
    } else if (blockIdx.x == 3) {
        for (int x = threadIdx.x; x < 2 * 64 * 8; x += 256) {
            int j = x & 7, lane = (x >> 3) & 63, ks = x >> 9;
            int m = lane & 15;
            int k = ks * 32 + (lane >> 4) * 8 + j;
            pWu2[x] = f2bf(Wu2[k * 16 + m]);
        }
    }

    // ---- last-block fused scan ----
    __threadfence();
    __shared__ int lastFlag;
    __shared__ int sw[4];
    if (threadIdx.x == 0)
        lastFlag = (atomicAdd(done, 1) == (int)gridDim.x - 1) ? 1 : 0;
    __syncthreads();
    if (!lastFlag) return;

    int t = threadIdx.x, lane = t & 63, wv = t >> 6;
    for (int s = 0; s < 2; s++) {
        const int* cnt = s ? cnt_b : cnt_a;
        int* start     = s ? start_b : start_a;
        int base = t * 128;
        const int4* p = (const int4*)(cnt + base);
        int sum = 0;
#pragma unroll 8
        for (int q = 0; q < 32; q++) { int4 v = p[q]; sum += v.x + v.y + v.z + v.w; }
        int inc = sum;
#pragma unroll
        for (int off = 1; off < 64; off <<= 1) {
            int u = __shfl_up(inc, off);
            if (lane >= off) inc += u;
        }
        if (lane == 63) sw[wv] = inc;
        __syncthreads();
        int woff = 0;
        for (int w = 0; w < wv; w++) woff += sw[w];
        int run = woff + inc - sum;
        int4* ps = (int4*)(start + base);
#pragma unroll 8
        for (int q = 0; q < 32; q++) {
            int4 v = p[q];
            int4 o;
            o.x = run; run += v.x;
            o.y = run; run += v.y;
            o.z = run; run += v.z;
            o.w = run; run += v.w;
            ps[q] = o;
        }
        __syncthreads();
    }
}

// ---------------- edge MLP via bf16 MFMA + absorbed eidx build (bb==0, non-atomic) ----
__global__ __launch_bounds__(256, 5) void edge_kernel(
    const unsigned short* __restrict__ nv16, const float* __restrict__ edge_vals,
    const int* __restrict__ ca, const int* __restrict__ cb,
    const int* __restrict__ rank_a, const int* __restrict__ rank_b,
    const int* __restrict__ start_a, const int* __restrict__ start_b,
    int* __restrict__ eidx_a, int* __restrict__ eidx_b,
    const unsigned short* __restrict__ pW1, const unsigned short* __restrict__ pW2,
    const float* __restrict__ bm2,
    float* __restrict__ out_edge,
    unsigned short* __restrict__ ma, unsigned short* __restrict__ mb)
{
    __shared__ unsigned short sH[256 * 64];   // 32768 B
    char* sB = (char*)sH;

    int t    = threadIdx.x;
    int lane = t & 63;
    int col  = lane & 15;
    int quad = lane >> 4;
    int erow = (t >> 6) * 64;
    int cha  = quad * 4;

    size_t eb  = (size_t)blockIdx.x * 256;
    size_t idx = eb + t;
    int e  = (int)(idx & (NE - 1));
    int bb = (int)(idx >> 18);

    int na = ca[e], nb = cb[e];

    // absorbed eidx: plain scattered 4B stores into L2-resident 1MB tables; no atomics.
    if (bb == 0) {
        eidx_a[start_a[na] + rank_a[e]] = e;
        eidx_b[start_b[nb] + rank_b[e]] = e;
    }

    {
        const uint4* gA = (const uint4*)(nv16 + ((size_t)bb * NN + na) * CV);
        const uint4* gB = (const uint4*)(nv16 + ((size_t)bb * NN + nb) * CV);
        uint4 a0 = gA[0], a1 = gA[1];
        uint4 b0 = gB[0], b1 = gB[1];
        const float4* pE = (const float4*)(edge_vals + idx * CE);
        float4 ev0 = pE[0], ev1 = pE[1], ev2 = pE[2], ev3 = pE[3];

        unsigned pk[32];
        *(uint4*)&pk[0]  = a0;  *(uint4*)&pk[4]  = a1;
        *(uint4*)&pk[8]  = b0;  *(uint4*)&pk[12] = b1;
        pk[16] = pk2bf(ev0.x, ev0.y); pk[17] = pk2bf(ev0.z, ev0.w);
        pk[18] = pk2bf(ev1.x, ev1.y); pk[19] = pk2bf(ev1.z, ev1.w);
        pk[20] = pk2bf(ev2.x, ev2.y); pk[21] = pk2bf(ev2.z, ev2.w);
        pk[22] = pk2bf(ev3.x, ev3.y); pk[23] = pk2bf(ev3.z, ev3.w);
        pk[24] = 0x3F80u;   // bias row: h[48] = 1.0
#pragma unroll
        for (int q = 25; q < 32; q++) pk[q] = 0;
        const uint4* src = (const uint4*)pk;
#pragma unroll
        for (int q = 0; q < 8; q++)
            *(uint4*)(sB + swo(t, q * 16)) = src[q];
    }
    asm volatile("s_waitcnt lgkmcnt(0)" ::: "memory");   // (1) own-wave h rows visible

#pragma unroll
    for (int hh = 0; hh < 2; hh++) {
        int r0 = erow + hh * 32 + col;

        frag w1f[4][2];
#pragma unroll
        for (int mt = 0; mt < 4; mt++)
#pragma unroll
            for (int ks = 0; ks < 2; ks++)
                w1f[mt][ks] = *(const frag*)&pW1[(((mt * 2 + ks) * 64) + lane) * 8];

        f32x4 acc1[4][2];
#pragma unroll
        for (int mt = 0; mt < 4; mt++)
#pragma unroll
            for (int n = 0; n < 2; n++) acc1[mt][n] = (f32x4){0.f, 0.f, 0.f, 0.f};

#pragma unroll
        for (int ks = 0; ks < 2; ks++) {
            frag bfr[2];
#pragma unroll
            for (int n = 0; n < 2; n++)
                bfr[n] = *(const frag*)(sB + swo(r0 + n * 16, ks * 64 + quad * 16));
#pragma unroll
            for (int mt = 0; mt < 4; mt++)
#pragma unroll
                for (int n = 0; n < 2; n++)
                    acc1[mt][n] = __builtin_amdgcn_mfma_f32_16x16x32_bf16(
                        w1f[mt][ks], bfr[n], acc1[mt][n], 0, 0, 0);
        }

#pragma unroll
        for (int n = 0; n < 2; n++) {
            int row = r0 + n * 16;
#pragma unroll
            for (int mt = 0; mt < 4; mt++) {
                uint2 w;
                w.x = pk2bf(fast_tanh(acc1[mt][n][0]), fast_tanh(acc1[mt][n][1]));
                w.y = pk2bf(fast_tanh(acc1[mt][n][2]), fast_tanh(acc1[mt][n][3]));
                *(uint2*)(sB + swo(row, mt * 32 + quad * 8)) = w;
            }
        }
        asm volatile("s_waitcnt lgkmcnt(0)" ::: "memory");  // (2) T rows of this half visible

        frag w2f[3][2];
#pragma unroll
        for (int mt = 0; mt < 3; mt++)
#pragma unroll
            for (int ks = 0; ks < 2; ks++)
                w2f[mt][ks] = *(const frag*)&pW2[(((mt * 2 + ks) * 64) + lane) * 8];

        f32x4 acc2[3][2];
#pragma unroll
        for (int mt = 0; mt < 3; mt++)
#pragma unroll
            for (int n = 0; n < 2; n++) acc2[mt][n] = (f32x4){0.f, 0.f, 0.f, 0.f};

#pragma unroll
        for (int ks = 0; ks < 2; ks++) {
            frag bfr[2];
#pragma unroll
            for (int n = 0; n < 2; n++)
                bfr[n] = *(const frag*)(sB + swo(r0 + n * 16, ks * 64 + quad * 16));
#pragma unroll
            for (int mt = 0; mt < 3; mt++)
#pragma unroll
                for (int n = 0; n < 2; n++)
                    acc2[mt][n] = __builtin_amdgcn_mfma_f32_16x16x32_bf16(
                        w2f[mt][ks], bfr[n], acc2[mt][n], 0, 0, 0);
        }

        // out_edge in-loop from acc2 (+ L2-hot re-read of this block's edge_vals range)
        float4 b2e = *(const float4*)&bm2[32 + cha];
#pragma unroll
        for (int n = 0; n < 2; n++) {
            int le = r0 + n * 16;
            size_t o = (eb + le) * CE + cha;
            float4 evv = *(const float4*)&edge_vals[o];
            float4 ov;
            ov.x = evv.x + acc2[2][n][0] + b2e.x;
            ov.y = evv.y + acc2[2][n][1] + b2e.y;
            ov.z = evv.z + acc2[2][n][2] + b2e.z;
            ov.w = evv.w + acc2[2][n][3] + b2e.w;
            *(float4*)&out_edge[o] = ov;
        }

        float4 b2a = *(const float4*)&bm2[cha];
        float4 b2b = *(const float4*)&bm2[16 + cha];
#pragma unroll
        for (int n = 0; n < 2; n++) {
            int row = r0 + n * 16;
            uint2 wa;
            wa.x = pk2bf(acc2[0][n][0] + b2a.x, acc2[0][n][1] + b2a.y);
            wa.y = pk2bf(acc2[0][n][2] + b2a.z, acc2[0][n][3] + b2a.w);
            *(uint2*)(sB + swo(row, quad * 8)) = wa;
            uint2 wb;
            wb.x = pk2bf(acc2[1][n][0] + b2b.x, acc2[1][n][1] + b2b.y);
            wb.y = pk2bf(acc2[1][n][2] + b2b.z, acc2[1][n][3] + b2b.w);
            *(uint2*)(sB + swo(row, 32 + quad * 8)) = wb;
        }
    }
    asm volatile("s_waitcnt lgkmcnt(0)" ::: "memory");   // (3) all m rows visible

    {
        uint4 a0 = *(const uint4*)(sB + swo(t, 0));
        uint4 a1 = *(const uint4*)(sB + swo(t, 16));
        uint4 b0 = *(const uint4*)(sB + swo(t, 32));
        uint4 b1 = *(const uint4*)(sB + swo(t, 48));
        unsigned short* pa = &ma[idx * 16];
        *(uint4*)(pa + 0) = a0;
        *(uint4*)(pa + 8) = a1;
        unsigned short* pb = &mb[idx * 16];
        *(uint4*)(pb + 0) = b0;
        *(uint4*)(pb + 8) = b1;
    }
}

// ---------------- fused gather-mean aggregation + node MLP (bf16 MFMA) + residual ------
// Round 11: 128-node blocks (grid 1024 x 256 thr, LDS 16 KB) -> 4 independent blocks/CU
// for cross-block gather/MFMA overlap. Threads 0-127 = a-stream, 128-255 = b-stream.
__global__ __launch_bounds__(256) void node_kernel(
    const float* __restrict__ node_vals,
    const unsigned short* __restrict__ ma, const unsigned short* __restrict__ mb,
    const int* __restrict__ eidx_a, const int* __restrict__ eidx_b,
    const int* __restrict__ start_a, const int* __restrict__ start_b,
    const int* __restrict__ cnt_a, const int* __restrict__ cnt_b,
    const unsigned short* __restrict__ pWu1, const unsigned short* __restrict__ pWu2,
    const float* __restrict__ bu2,
    float* __restrict__ out_node)
{
    __shared__ unsigned short sH[128 * 64];   // 16384 B
    char* sB = (char*)sH;

    int t    = threadIdx.x;      // 0..255
    int tn   = t & 127;          // node slot within block
    int half = t >> 7;           // 0 = a-stream, 1 = b-stream
    int g = blockIdx.x * 128 + tn;
    int n = g & (NN - 1);
    int b = g >> 15;

    float4 pn[4];   // valid for half==0 threads

    {
        const int* cntp = half ? cnt_b : cnt_a;
        const int* stp  = half ? start_b : start_a;
        const int* ep   = half ? eidx_b : eidx_a;
        const unsigned short* mp = (half ? mb : ma) + (size_t)b * NE * 16;

        int d = cntp[n], s = stp[n];
        const int* ix = ep + s;

        float u[16] = {0.f,0.f,0.f,0.f,0.f,0.f,0.f,0.f,0.f,0.f,0.f,0.f,0.f,0.f,0.f,0.f};
        for (int k0 = 0; k0 < d; k0 += 4) {
            uint4 v[4][2];
            int nn_ = d - k0; nn_ = (nn_ > 4) ? 4 : nn_;
#pragma unroll
            for (int j = 0; j < 4; j++) {
                if (j < nn_) {
                    int ee = ix[k0 + j];
                    const uint4* p = (const uint4*)(mp + (size_t)ee * 16);
                    v[j][0] = p[0]; v[j][1] = p[1];
                }
            }
#pragma unroll
            for (int j = 0; j < 4; j++) {
                if (j < nn_) { acc8(&u[0], v[j][0]); acc8(&u[8], v[j][1]); }
            }
        }
        float inv = 1.0f / (float)max(d, 1);
        unsigned pk[8];
#pragma unroll
        for (int q = 0; q < 8; q++) pk[q] = pk2bf(u[2*q] * inv, u[2*q+1] * inv);
        *(uint4*)(sB + swo(tn, half * 32 + 0))  = ((const uint4*)pk)[0];
        *(uint4*)(sB + swo(tn, half * 32 + 16)) = ((const uint4*)pk)[1];

        if (half == 0) {
            const float4* pnv = (const float4*)(node_vals + (size_t)g * CV);
#pragma unroll
            for (int q = 0; q < 4; q++) pn[q] = pnv[q];
            unsigned pk2[16];
#pragma unroll
            for (int q = 0; q < 4; q++) {
                pk2[2*q + 0] = pk2bf(pn[q].x, pn[q].y);
                pk2[2*q + 1] = pk2bf(pn[q].z, pn[q].w);
            }
            pk2[8] = 0x3F80u;   // bias row: u[48] = 1.0 (bu1 folded into pWu1 row 48)
#pragma unroll
            for (int q = 9; q < 16; q++) pk2[q] = 0;
#pragma unroll
            for (int q = 0; q < 4; q++)
                *(uint4*)(sB + swo(tn, 64 + q * 16)) = ((const uint4*)pk2)[q];
        }
    }
    __syncthreads();   // (1) all u rows complete (cross-wave)

    // ---- MFMA phase: wave wv (0..3) -> band wv&1, half hh = wv>>1 ----
    {
        int lane = t & 63;
        int col  = lane & 15;
        int quad = lane >> 4;
        int wv   = t >> 6;
        int band = wv & 1;
        int hh   = wv >> 1;
        int r0 = band * 64 + hh * 32 + col;

        frag w1f[4][2];
#pragma unroll
        for (int mt = 0; mt < 4; mt++)
#pragma unroll
            for (int ks = 0; ks < 2; ks++)
                w1f[mt][ks] = *(const frag*)&pWu1[(((mt * 2 + ks) * 64) + lane) * 8];

        f32x4 acc1[4][2];
#pragma unroll
        for (int mt = 0; mt < 4; mt++)
#pragma unroll
            for (int nt = 0; nt < 2; nt++) acc1[mt][nt] = (f32x4){0.f, 0.f, 0.f, 0.f};

#pragma unroll
        for (int ks = 0; ks < 2; ks++) {
            frag bfr[2];
#pragma unroll
            for (int nt = 0; nt < 2; nt++)
                bfr[nt] = *(const frag*)(sB + swo(r0 + nt * 16, ks * 64 + quad * 16));
#pragma unroll
            for (int mt = 0; mt < 4; mt++)
#pragma unroll
                for (int nt = 0; nt < 2; nt++)
                    acc1[mt][nt] = __builtin_amdgcn_mfma_f32_16x16x32_bf16(
                        w1f[mt][ks], bfr[nt], acc1[mt][nt], 0, 0, 0);
        }

#pragma unroll
        for (int nt = 0; nt < 2; nt++) {
            int row = r0 + nt * 16;
#pragma unroll
            for (int mt = 0; mt < 4; mt++) {
                uint2 w;
                w.x = pk2bf(fast_tanh(acc1[mt][nt][0]), fast_tanh(acc1[mt][nt][1]));
                w.y = pk2bf(fast_tanh(acc1[mt][nt][2]), fast_tanh(acc1[mt][nt][3]));
                *(uint2*)(sB + swo(row, mt * 32 + quad * 8)) = w;
            }
        }
        asm volatile("s_waitcnt lgkmcnt(0)" ::: "memory");   // T rows (wave-local)

        frag w2f[2];
#pragma unroll
        for (int ks = 0; ks < 2; ks++)
            w2f[ks] = *(const frag*)&pWu2[(ks * 64 + lane) * 8];

        f32x4 acc2[2];
#pragma unroll
        for (int nt = 0; nt < 2; nt++) acc2[nt] = (f32x4){0.f, 0.f, 0.f, 0.f};

#pragma unroll
        for (int ks = 0; ks < 2; ks++) {
            frag bfr[2];
#pragma unroll
            for (int nt = 0; nt < 2; nt++)
                bfr[nt] = *(const frag*)(sB + swo(r0 + nt * 16, ks * 64 + quad * 16));
#pragma unroll
            for (int nt = 0; nt < 2; nt++)
                acc2[nt] = __builtin_amdgcn_mfma_f32_16x16x32_bf16(
                    w2f[ks], bfr[nt], acc2[nt], 0, 0, 0);
        }

#pragma unroll
        for (int nt = 0; nt < 2; nt++) {
            int row = r0 + nt * 16;
            float4 v;
            v.x = acc2[nt][0]; v.y = acc2[nt][1];
            v.z = acc2[nt][2]; v.w = acc2[nt][3];
            *(float4*)(sB + swo(row, 64 + quad * 16)) = v;
        }
    }
    __syncthreads();   // (2) all update rows complete (cross-wave)

    if (half == 0) {
        const float4* pb2 = (const float4*)bu2;
        float4* po = (float4*)&out_node[(size_t)g * CV];
#pragma unroll
        for (int q = 0; q < 4; q++) {
            float4 m = *(const float4*)(sB + swo(tn, 64 + q * 16));
            float4 c = pb2[q];
            float4 o;
            o.x = pn[q].x + m.x + c.x;
            o.y = pn[q].y + m.y + c.y;
            o.z = pn[q].z + m.z + c.z;
            o.w = pn[q].w + m.w + c.w;
            po[q] = o;
        }
    }
}

extern "C" void kernel_launch(void* const* d_in, const int* in_sizes, int n_in,
                              void* d_out, int out_size, void* d_ws, size_t ws_size,
                              hipStream_t stream) {
    const float* node_vals = (const float*)d_in[0];
    const float* edge_vals = (const float*)d_in[1];
    const int*   ca        = (const int*)d_in[2];
    const int*   cb        = (const int*)d_in[3];
    const float* Wm1 = (const float*)d_in[4];
    const float* bm1 = (const float*)d_in[5];
    const float* Wm2 = (const float*)d_in[6];
    const float* bm2 = (const float*)d_in[7];
    const float* Wu1 = (const float*)d_in[8];
    const float* bu1 = (const float*)d_in[9];
    const float* Wu2 = (const float*)d_in[10];
    const float* bu2 = (const float*)d_in[11];

    float* out_node = (float*)d_out;
    float* out_edge = out_node + (size_t)B * NN * CV;

    unsigned short* ma = (unsigned short*)d_ws;                   // B*NE*16 bf16 (32 MB)
    unsigned short* mb = ma + (size_t)B * NE * 16;                // 32 MB
    int* cnt_a   = (int*)(mb + (size_t)B * NE * 16);
    int* cnt_b   = cnt_a + NN;
    int* done    = cnt_b + NN;                                    // 4 ints (padding for align)
    int* start_a = done + 4;
    int* start_b = start_a + NN;
    int* rank_a  = start_b + NN;
    int* rank_b  = rank_a + NE;
    int* eidx_a  = rank_b + NE;                                   // NE ints (1 MB)
    int* eidx_b  = eidx_a + NE;                                   // 1 MB
    unsigned short* pW1  = (unsigned short*)(eidx_b + NE);        // 4096 bf16
    unsigned short* pW2  = pW1 + 4096;                            // 3072 bf16
    unsigned short* pWu1 = pW2 + 3072;                            // 4096 bf16
    unsigned short* pWu2 = pWu1 + 4096;                           // 1024 bf16
    unsigned short* nv16 = pWu2 + 1024;                           // B*NN*CV bf16 (4 MB)

    hipMemsetAsync(cnt_a, 0, (2 * (size_t)NN + 4) * sizeof(int), stream);

    count_kernel<<<NE / 256, 256, 0, stream>>>(
        ca, cb, cnt_a, cnt_b, rank_a, rank_b, start_a, start_b, done,
        Wm1, bm1, Wm2, Wu1, bu1, Wu2, node_vals,
        pW1, pW2, pWu1, pWu2, nv16);
    edge_kernel<<<(B * NE) / 256, 256, 0, stream>>>(
        nv16, edge_vals, ca, cb, rank_a, rank_b, start_a, start_b, eidx_a, eidx_b,
        pW1, pW2, bm2, out_edge, ma, mb);
    node_kernel<<<(B * NN) / 128, 256, 0, stream>>>(
        node_vals, ma, mb, eidx_a, eidx_b, start_a, start_b, cnt_a, cnt_b,
        pWu1, pWu2, bu2, out_node);
}

// Round 12
// 281.677 us; speedup vs baseline: 1.4606x; 1.4606x over previous
//
#include <hip/hip_runtime.h>
#include <hip/hip_bf16.h>
#include <cstdint>
#include <cstddef>

#define B 4
#define NN 32768
#define NE 262144
#define CV 16
#define CE 16
#define HID 64
#define CM 48   // 2*CV + CE

using frag  = __attribute__((ext_vector_type(8))) short;
using f32x4 = __attribute__((ext_vector_type(4))) float;

__device__ __forceinline__ float fast_tanh(float x) {
    float e = __expf(2.0f * x);
    return 1.0f - 2.0f / (e + 1.0f);
}

__device__ __forceinline__ unsigned short f2bf(float x) {
    union { float f; unsigned u; } v; v.f = x;
    unsigned r = (v.u + 0x7FFFu + ((v.u >> 16) & 1u)) >> 16;
    return (unsigned short)r;
}

__device__ __forceinline__ float bf2f(unsigned short x) {
    union { unsigned u; float f; } v; v.u = ((unsigned)x) << 16;
    return v.f;
}

__device__ __forceinline__ unsigned pk2bf(float lo, float hi) {
    union { __hip_bfloat162 h; unsigned u; } v;
    v.h = __float22bfloat162_rn(make_float2(lo, hi));
    return v.u;
}

// wave-private swizzled LDS offset: 128 B row stride; XOR byte bits 4..6 with row&7
__device__ __forceinline__ unsigned swo(int row, int byte_off) {
    return (unsigned)((row << 7) + (byte_off ^ ((row & 7) << 4)));
}

__device__ __forceinline__ void acc8(float* a, uint4 v) {
    a[0] += bf2f((unsigned short)(v.x & 0xFFFFu));
    a[1] += bf2f((unsigned short)(v.x >> 16));
    a[2] += bf2f((unsigned short)(v.y & 0xFFFFu));
    a[3] += bf2f((unsigned short)(v.y >> 16));
    a[4] += bf2f((unsigned short)(v.z & 0xFFFFu));
    a[5] += bf2f((unsigned short)(v.z >> 16));
    a[6] += bf2f((unsigned short)(v.w & 0xFFFFu));
    a[7] += bf2f((unsigned short)(v.w >> 16));
}

// ---------------- degree counts + rank + weight prepack + bf16 node table (R10) -------
__global__ __launch_bounds__(256) void count_kernel(
    const int* __restrict__ ca, const int* __restrict__ cb,
    int* __restrict__ cnt_a, int* __restrict__ cnt_b,
    int* __restrict__ rank_a, int* __restrict__ rank_b,
    const float* __restrict__ Wm1, const float* __restrict__ bm1,
    const float* __restrict__ Wm2,
    const float* __restrict__ Wu1, const float* __restrict__ bu1,
    const float* __restrict__ Wu2,
    const float* __restrict__ node_vals,
    unsigned short* __restrict__ pW1, unsigned short* __restrict__ pW2,
    unsigned short* __restrict__ pWu1, unsigned short* __restrict__ pWu2,
    unsigned short* __restrict__ nv16)
{
    int i = blockIdx.x * 256 + threadIdx.x;
    rank_a[i] = atomicAdd(&cnt_a[ca[i]], 1);
    rank_b[i] = atomicAdd(&cnt_b[cb[i]], 1);

    {
        int x0 = i * 8;
        const float4* src = (const float4*)(node_vals + x0);
        float4 v0 = src[0], v1 = src[1];
        uint4 o;
        o.x = pk2bf(v0.x, v0.y); o.y = pk2bf(v0.z, v0.w);
        o.z = pk2bf(v1.x, v1.y); o.w = pk2bf(v1.z, v1.w);
        *(uint4*)(nv16 + x0) = o;
    }

    if (blockIdx.x == 0) {
        for (int x = threadIdx.x; x < 4 * 2 * 64 * 8; x += 256) {
            int j = x & 7, lane = (x >> 3) & 63, ks = (x >> 9) & 1, mt = x >> 10;
            int m = mt * 16 + (lane & 15);
            int k = ks * 32 + (lane >> 4) * 8 + j;
            float w = (k < 48) ? Wm1[k * 64 + m] : (k == 48 ? bm1[m] : 0.0f);
            pW1[x] = f2bf(w);
        }
    } else if (blockIdx.x == 1) {
        for (int x = threadIdx.x; x < 3 * 2 * 64 * 8; x += 256) {
            int j = x & 7, lane = (x >> 3) & 63, ks = (x >> 9) & 1, mt = x >> 10;
            int m = mt * 16 + (lane & 15);
            int k = ks * 32 + (lane >> 4) * 8 + j;
            pW2[x] = f2bf(Wm2[k * 48 + m]);
        }
    } else if (blockIdx.x == 2) {
        for (int x = threadIdx.x; x < 4 * 2 * 64 * 8; x += 256) {
            int j = x & 7, lane = (x >> 3) & 63, ks = (x >> 9) & 1, mt = x >> 10;
            int m = mt * 16 + (lane & 15);
            int k = ks * 32 + (lane >> 4) * 8 + j;
            float w = (k < 48) ? Wu1[k * 64 + m] : (k == 48 ? bu1[m] : 0.0f);
            pWu1[x] = f2bf(w);
        }
    } else if (blockIdx.x == 3) {
        for (int x = threadIdx.x; x < 2 * 64 * 8; x += 256) {
            int j = x & 7, lane = (x >> 3) & 63, ks = x >> 9;
            int m = lane & 15;
            int k = ks * 32 + (lane >> 4) * 8 + j;
            pWu2[x] = f2bf(Wu2[k * 16 + m]);
        }
    }
}

// ---------------- exclusive prefix sum over NN bins (2 blocks: a and b) ----------------
__global__ __launch_bounds__(1024) void scan_kernel(
    const int* __restrict__ cnt_a, int* __restrict__ start_a,
    const int* __restrict__ cnt_b, int* __restrict__ start_b)
{
    const int* cnt = (blockIdx.x == 0) ? cnt_a : cnt_b;
    int* start     = (blockIdx.x == 0) ? start_a : start_b;

    __shared__ int sw[16];
    int t = threadIdx.x;
    int lane = t & 63;
    int wv   = t >> 6;
    int base = t * 32;

    int local[32];
    int sum = 0;
    const int4* p = (const int4*)(cnt + base);
#pragma unroll
    for (int q = 0; q < 8; q++) {
        int4 v = p[q];
        local[q*4+0] = v.x; local[q*4+1] = v.y; local[q*4+2] = v.z; local[q*4+3] = v.w;
        sum += v.x + v.y + v.z + v.w;
    }
    int inc = sum;
#pragma unroll
    for (int off = 1; off < 64; off <<= 1) {
        int u = __shfl_up(inc, off);
        if (lane >= off) inc += u;
    }
    if (lane == 63) sw[wv] = inc;
    __syncthreads();
    if (wv == 0 && lane < 16) {
        int v = sw[lane];
        int i2 = v;
#pragma unroll
        for (int off = 1; off < 16; off <<= 1) {
            int u = __shfl_up(i2, off);
            if (lane >= off) i2 += u;
        }
        sw[lane] = i2 - v;
    }
    __syncthreads();

    int run = sw[wv] + inc - sum;
    int4* ps = (int4*)(start + base);
#pragma unroll
    for (int q = 0; q < 8; q++) {
        int4 o;
        o.x = run; run += local[q*4+0];
        o.y = run; run += local[q*4+1];
        o.z = run; run += local[q*4+2];
        o.w = run; run += local[q*4+3];
        ps[q] = o;
    }
}

// ---------------- edge MLP via bf16 MFMA + absorbed eidx (bb==0, plain stores) --------
__global__ __launch_bounds__(256, 5) void edge_kernel(
    const unsigned short* __restrict__ nv16, const float* __restrict__ edge_vals,
    const int* __restrict__ ca, const int* __restrict__ cb,
    const int* __restrict__ rank_a, const int* __restrict__ rank_b,
    const int* __restrict__ start_a, const int* __restrict__ start_b,
    int* __restrict__ eidx_a, int* __restrict__ eidx_b,
    const unsigned short* __restrict__ pW1, const unsigned short* __restrict__ pW2,
    const float* __restrict__ bm2,
    float* __restrict__ out_edge,
    unsigned short* __restrict__ ma, unsigned short* __restrict__ mb)
{
    __shared__ unsigned short sH[256 * 64];   // 32768 B
    char* sB = (char*)sH;

    int t    = threadIdx.x;
    int lane = t & 63;
    int col  = lane & 15;
    int quad = lane >> 4;
    int erow = (t >> 6) * 64;
    int cha  = quad * 4;

    size_t eb  = (size_t)blockIdx.x * 256;
    size_t idx = eb + t;
    int e  = (int)(idx & (NE - 1));
    int bb = (int)(idx >> 18);

    int na = ca[e], nb = cb[e];

    // absorbed eidx: plain scattered 4B stores into L2-resident 1MB tables; no atomics.
    if (bb == 0) {
        eidx_a[start_a[na] + rank_a[e]] = e;
        eidx_b[start_b[nb] + rank_b[e]] = e;
    }

    {
        const uint4* gA = (const uint4*)(nv16 + ((size_t)bb * NN + na) * CV);
        const uint4* gB = (const uint4*)(nv16 + ((size_t)bb * NN + nb) * CV);
        uint4 a0 = gA[0], a1 = gA[1];
        uint4 b0 = gB[0], b1 = gB[1];
        const float4* pE = (const float4*)(edge_vals + idx * CE);
        float4 ev0 = pE[0], ev1 = pE[1], ev2 = pE[2], ev3 = pE[3];

        unsigned pk[32];
        *(uint4*)&pk[0]  = a0;  *(uint4*)&pk[4]  = a1;
        *(uint4*)&pk[8]  = b0;  *(uint4*)&pk[12] = b1;
        pk[16] = pk2bf(ev0.x, ev0.y); pk[17] = pk2bf(ev0.z, ev0.w);
        pk[18] = pk2bf(ev1.x, ev1.y); pk[19] = pk2bf(ev1.z, ev1.w);
        pk[20] = pk2bf(ev2.x, ev2.y); pk[21] = pk2bf(ev2.z, ev2.w);
        pk[22] = pk2bf(ev3.x, ev3.y); pk[23] = pk2bf(ev3.z, ev3.w);
        pk[24] = 0x3F80u;   // bias row: h[48] = 1.0
#pragma unroll
        for (int q = 25; q < 32; q++) pk[q] = 0;
        const uint4* src = (const uint4*)pk;
#pragma unroll
        for (int q = 0; q < 8; q++)
            *(uint4*)(sB + swo(t, q * 16)) = src[q];
    }
    asm volatile("s_waitcnt lgkmcnt(0)" ::: "memory");   // (1) own-wave h rows visible

#pragma unroll
    for (int hh = 0; hh < 2; hh++) {
        int r0 = erow + hh * 32 + col;

        frag w1f[4][2];
#pragma unroll
        for (int mt = 0; mt < 4; mt++)
#pragma unroll
            for (int ks = 0; ks < 2; ks++)
                w1f[mt][ks] = *(const frag*)&pW1[(((mt * 2 + ks) * 64) + lane) * 8];

        f32x4 acc1[4][2];
#pragma unroll
        for (int mt = 0; mt < 4; mt++)
#pragma unroll
            for (int n = 0; n < 2; n++) acc1[mt][n] = (f32x4){0.f, 0.f, 0.f, 0.f};

#pragma unroll
        for (int ks = 0; ks < 2; ks++) {
            frag bfr[2];
#pragma unroll
            for (int n = 0; n < 2; n++)
                bfr[n] = *(const frag*)(sB + swo(r0 + n * 16, ks * 64 + quad * 16));
#pragma unroll
            for (int mt = 0; mt < 4; mt++)
#pragma unroll
                for (int n = 0; n < 2; n++)
                    acc1[mt][n] = __builtin_amdgcn_mfma_f32_16x16x32_bf16(
                        w1f[mt][ks], bfr[n], acc1[mt][n], 0, 0, 0);
        }

#pragma unroll
        for (int n = 0; n < 2; n++) {
            int row = r0 + n * 16;
#pragma unroll
            for (int mt = 0; mt < 4; mt++) {
                uint2 w;
                w.x = pk2bf(fast_tanh(acc1[mt][n][0]), fast_tanh(acc1[mt][n][1]));
                w.y = pk2bf(fast_tanh(acc1[mt][n][2]), fast_tanh(acc1[mt][n][3]));
                *(uint2*)(sB + swo(row, mt * 32 + quad * 8)) = w;
            }
        }
        asm volatile("s_waitcnt lgkmcnt(0)" ::: "memory");  // (2) T rows of this half visible

        frag w2f[3][2];
#pragma unroll
        for (int mt = 0; mt < 3; mt++)
#pragma unroll
            for (int ks = 0; ks < 2; ks++)
                w2f[mt][ks] = *(const frag*)&pW2[(((mt * 2 + ks) * 64) + lane) * 8];

        f32x4 acc2[3][2];
#pragma unroll
        for (int mt = 0; mt < 3; mt++)
#pragma unroll
            for (int n = 0; n < 2; n++) acc2[mt][n] = (f32x4){0.f, 0.f, 0.f, 0.f};

#pragma unroll
        for (int ks = 0; ks < 2; ks++) {
            frag bfr[2];
#pragma unroll
            for (int n = 0; n < 2; n++)
                bfr[n] = *(const frag*)(sB + swo(r0 + n * 16, ks * 64 + quad * 16));
#pragma unroll
            for (int mt = 0; mt < 3; mt++)
#pragma unroll
                for (int n = 0; n < 2; n++)
                    acc2[mt][n] = __builtin_amdgcn_mfma_f32_16x16x32_bf16(
                        w2f[mt][ks], bfr[n], acc2[mt][n], 0, 0, 0);
        }

        // out_edge in-loop from acc2 (+ L2-hot re-read of this block's edge_vals range)
        float4 b2e = *(const float4*)&bm2[32 + cha];
#pragma unroll
        for (int n = 0; n < 2; n++) {
            int le = r0 + n * 16;
            size_t o = (eb + le) * CE + cha;
            float4 evv = *(const float4*)&edge_vals[o];
            float4 ov;
            ov.x = evv.x + acc2[2][n][0] + b2e.x;
            ov.y = evv.y + acc2[2][n][1] + b2e.y;
            ov.z = evv.z + acc2[2][n][2] + b2e.z;
            ov.w = evv.w + acc2[2][n][3] + b2e.w;
            *(float4*)&out_edge[o] = ov;
        }

        float4 b2a = *(const float4*)&bm2[cha];
        float4 b2b = *(const float4*)&bm2[16 + cha];
#pragma unroll
        for (int n = 0; n < 2; n++) {
            int row = r0 + n * 16;
            uint2 wa;
            wa.x = pk2bf(acc2[0][n][0] + b2a.x, acc2[0][n][1] + b2a.y);
            wa.y = pk2bf(acc2[0][n][2] + b2a.z, acc2[0][n][3] + b2a.w);
            *(uint2*)(sB + swo(row, quad * 8)) = wa;
            uint2 wb;
            wb.x = pk2bf(acc2[1][n][0] + b2b.x, acc2[1][n][1] + b2b.y);
            wb.y = pk2bf(acc2[1][n][2] + b2b.z, acc2[1][n][3] + b2b.w);
            *(uint2*)(sB + swo(row, 32 + quad * 8)) = wb;
        }
    }
    asm volatile("s_waitcnt lgkmcnt(0)" ::: "memory");   // (3) all m rows visible

    {
        uint4 a0 = *(const uint4*)(sB + swo(t, 0));
        uint4 a1 = *(const uint4*)(sB + swo(t, 16));
        uint4 b0 = *(const uint4*)(sB + swo(t, 32));
        uint4 b1 = *(const uint4*)(sB + swo(t, 48));
        unsigned short* pa = &ma[idx * 16];
        *(uint4*)(pa + 0) = a0;
        *(uint4*)(pa + 8) = a1;
        unsigned short* pb = &mb[idx * 16];
        *(uint4*)(pb + 0) = b0;
        *(uint4*)(pb + 8) = b1;
    }
}

// ---------------- fused gather-mean aggregation + node MLP (R10's 512-thread version) --
__global__ __launch_bounds__(512) void node_kernel(
    const float* __restrict__ node_vals,
    const unsigned short* __restrict__ ma, const unsigned short* __restrict__ mb,
    const int* __restrict__ eidx_a, const int* __restrict__ eidx_b,
    const int* __restrict__ start_a, const int* __restrict__ start_b,
    const int* __restrict__ cnt_a, const int* __restrict__ cnt_b,
    const unsigned short* __restrict__ pWu1, const unsigned short* __restrict__ pWu2,
    const float* __restrict__ bu2,
    float* __restrict__ out_node)
{
    __shared__ unsigned short sH[256 * 64];   // 32768 B
    char* sB = (char*)sH;

    int t    = threadIdx.x;      // 0..511
    int tn   = t & 255;          // node slot within block
    int half = t >> 8;           // 0 = a-stream, 1 = b-stream
    int g = blockIdx.x * 256 + tn;
    int n = g & (NN - 1);
    int b = g >> 15;

    float4 pn[4];   // valid for half==0 threads

    {
        const int* cntp = half ? cnt_b : cnt_a;
        const int* stp  = half ? start_b : start_a;
        const int* ep   = half ? eidx_b : eidx_a;
        const unsigned short* mp = (half ? mb : ma) + (size_t)b * NE * 16;

        int d = cntp[n], s = stp[n];
        const int* ix = ep + s;

        float u[16] = {0.f,0.f,0.f,0.f,0.f,0.f,0.f,0.f,0.f,0.f,0.f,0.f,0.f,0.f,0.f,0.f};
        for (int k0 = 0; k0 < d; k0 += 4) {
            uint4 v[4][2];
            int nn_ = d - k0; nn_ = (nn_ > 4) ? 4 : nn_;
#pragma unroll
            for (int j = 0; j < 4; j++) {
                if (j < nn_) {
                    int ee = ix[k0 + j];
                    const uint4* p = (const uint4*)(mp + (size_t)ee * 16);
                    v[j][0] = p[0]; v[j][1] = p[1];
                }
            }
#pragma unroll
            for (int j = 0; j < 4; j++) {
                if (j < nn_) { acc8(&u[0], v[j][0]); acc8(&u[8], v[j][1]); }
            }
        }
        float inv = 1.0f / (float)max(d, 1);
        unsigned pk[8];
#pragma unroll
        for (int q = 0; q < 8; q++) pk[q] = pk2bf(u[2*q] * inv, u[2*q+1] * inv);
        *(uint4*)(sB + swo(tn, half * 32 + 0))  = ((const uint4*)pk)[0];
        *(uint4*)(sB + swo(tn, half * 32 + 16)) = ((const uint4*)pk)[1];

        if (half == 0) {
            const float4* pnv = (const float4*)(node_vals + (size_t)g * CV);
#pragma unroll
            for (int q = 0; q < 4; q++) pn[q] = pnv[q];
            unsigned pk2[16];
#pragma unroll
            for (int q = 0; q < 4; q++) {
                pk2[2*q + 0] = pk2bf(pn[q].x, pn[q].y);
                pk2[2*q + 1] = pk2bf(pn[q].z, pn[q].w);
            }
            pk2[8] = 0x3F80u;   // bias row: u[48] = 1.0 (bu1 folded into pWu1 row 48)
#pragma unroll
            for (int q = 9; q < 16; q++) pk2[q] = 0;
#pragma unroll
            for (int q = 0; q < 4; q++)
                *(uint4*)(sB + swo(tn, 64 + q * 16)) = ((const uint4*)pk2)[q];
        }
    }
    __syncthreads();   // (1) all u rows complete (cross-wave)

    // ---- MFMA phase: wave wv -> band wv&3, half hh = wv>>2 ----
    {
        int lane = t & 63;
        int col  = lane & 15;
        int quad = lane >> 4;
        int wv   = t >> 6;
        int band = wv & 3;
        int hh   = wv >> 2;
        int r0 = band * 64 + hh * 32 + col;

        frag w1f[4][2];
#pragma unroll
        for (int mt = 0; mt < 4; mt++)
#pragma unroll
            for (int ks = 0; ks < 2; ks++)
                w1f[mt][ks] = *(const frag*)&pWu1[(((mt * 2 + ks) * 64) + lane) * 8];

        f32x4 acc1[4][2];
#pragma unroll
        for (int mt = 0; mt < 4; mt++)
#pragma unroll
            for (int nt = 0; nt < 2; nt++) acc1[mt][nt] = (f32x4){0.f, 0.f, 0.f, 0.f};

#pragma unroll
        for (int ks = 0; ks < 2; ks++) {
            frag bfr[2];
#pragma unroll
            for (int nt = 0; nt < 2; nt++)
                bfr[nt] = *(const frag*)(sB + swo(r0 + nt * 16, ks * 64 + quad * 16));
#pragma unroll
            for (int mt = 0; mt < 4; mt++)
#pragma unroll
                for (int nt = 0; nt < 2; nt++)
                    acc1[mt][nt] = __builtin_amdgcn_mfma_f32_16x16x32_bf16(
                        w1f[mt][ks], bfr[nt], acc1[mt][nt], 0, 0, 0);
        }

#pragma unroll
        for (int nt = 0; nt < 2; nt++) {
            int row = r0 + nt * 16;
#pragma unroll
            for (int mt = 0; mt < 4; mt++) {
                uint2 w;
                w.x = pk2bf(fast_tanh(acc1[mt][nt][0]), fast_tanh(acc1[mt][nt][1]));
                w.y = pk2bf(fast_tanh(acc1[mt][nt][2]), fast_tanh(acc1[mt][nt][3]));
                *(uint2*)(sB + swo(row, mt * 32 + quad * 8)) = w;
            }
        }
        asm volatile("s_waitcnt lgkmcnt(0)" ::: "memory");   // T rows (wave-local)

        frag w2f[2];
#pragma unroll
        for (int ks = 0; ks < 2; ks++)
            w2f[ks] = *(const frag*)&pWu2[(ks * 64 + lane) * 8];

        f32x4 acc2[2];
#pragma unroll
        for (int nt = 0; nt < 2; nt++) acc2[nt] = (f32x4){0.f, 0.f, 0.f, 0.f};

#pragma unroll
        for (int ks = 0; ks < 2; ks++) {
            frag bfr[2];
#pragma unroll
            for (int nt = 0; nt < 2; nt++)
                bfr[nt] = *(const frag*)(sB + swo(r0 + nt * 16, ks * 64 + quad * 16));
#pragma unroll
            for (int nt = 0; nt < 2; nt++)
                acc2[nt] = __builtin_amdgcn_mfma_f32_16x16x32_bf16(
                    w2f[ks], bfr[nt], acc2[nt], 0, 0, 0);
        }

#pragma unroll
        for (int nt = 0; nt < 2; nt++) {
            int row = r0 + nt * 16;
            float4 v;
            v.x = acc2[nt][0]; v.y = acc2[nt][1];
            v.z = acc2[nt][2]; v.w = acc2[nt][3];
            *(float4*)(sB + swo(row, 64 + quad * 16)) = v;
        }
    }
    __syncthreads();   // (2) all update rows complete (cross-wave)

    if (half == 0) {
        const float4* pb2 = (const float4*)bu2;
        float4* po = (float4*)&out_node[(size_t)g * CV];
#pragma unroll
        for (int q = 0; q < 4; q++) {
            float4 m = *(const float4*)(sB + swo(tn, 64 + q * 16));
            float4 c = pb2[q];
            float4 o;
            o.x = pn[q].x + m.x + c.x;
            o.y = pn[q].y + m.y + c.y;
            o.z = pn[q].z + m.z + c.z;
            o.w = pn[q].w + m.w + c.w;
            po[q] = o;
        }
    }
}

extern "C" void kernel_launch(void* const* d_in, const int* in_sizes, int n_in,
                              void* d_out, int out_size, void* d_ws, size_t ws_size,
                              hipStream_t stream) {
    const float* node_vals = (const float*)d_in[0];
    const float* edge_vals = (const float*)d_in[1];
    const int*   ca        = (const int*)d_in[2];
    const int*   cb        = (const int*)d_in[3];
    const float* Wm1 = (const float*)d_in[4];
    const float* bm1 = (const float*)d_in[5];
    const float* Wm2 = (const float*)d_in[6];
    const float* bm2 = (const float*)d_in[7];
    const float* Wu1 = (const float*)d_in[8];
    const float* bu1 = (const float*)d_in[9];
    const float* Wu2 = (const float*)d_in[10];
    const float* bu2 = (const float*)d_in[11];

    float* out_node = (float*)d_out;
    float* out_edge = out_node + (size_t)B * NN * CV;

    unsigned short* ma = (unsigned short*)d_ws;                   // B*NE*16 bf16 (32 MB)
    unsigned short* mb = ma + (size_t)B * NE * 16;                // 32 MB
    int* cnt_a   = (int*)(mb + (size_t)B * NE * 16);
    int* cnt_b   = cnt_a + NN;
    int* start_a = cnt_b + NN;
    int* start_b = start_a + NN;
    int* rank_a  = start_b + NN;
    int* rank_b  = rank_a + NE;
    int* eidx_a  = rank_b + NE;                                   // NE ints (1 MB)
    int* eidx_b  = eidx_a + NE;                                   // 1 MB
    unsigned short* pW1  = (unsigned short*)(eidx_b + NE);        // 4096 bf16
    unsigned short* pW2  = pW1 + 4096;                            // 3072 bf16
    unsigned short* pWu1 = pW2 + 3072;                            // 4096 bf16
    unsigned short* pWu2 = pWu1 + 4096;                           // 1024 bf16
    unsigned short* nv16 = pWu2 + 1024;                           // B*NN*CV bf16 (4 MB)

    hipMemsetAsync(cnt_a, 0, 2 * (size_t)NN * sizeof(int), stream);

    count_kernel<<<NE / 256, 256, 0, stream>>>(
        ca, cb, cnt_a, cnt_b, rank_a, rank_b,
        Wm1, bm1, Wm2, Wu1, bu1, Wu2, node_vals,
        pW1, pW2, pWu1, pWu2, nv16);
    scan_kernel<<<2, 1024, 0, stream>>>(cnt_a, start_a, cnt_b, start_b);
    edge_kernel<<<(B * NE) / 256, 256, 0, stream>>>(
        nv16, edge_vals, ca, cb, rank_a, rank_b, start_a, start_b, eidx_a, eidx_b,
        pW1, pW2, bm2, out_edge, ma, mb);
    node_kernel<<<(B * NN) / 256, 512, 0, stream>>>(
        node_vals, ma, mb, eidx_a, eidx_b, start_a, start_b, cnt_a, cnt_b,
        pWu1, pWu2, bu2, out_node);
}

// Round 13
// 275.820 us; speedup vs baseline: 1.4916x; 1.0212x over previous
//
#include <hip/hip_runtime.h>
#include <hip/hip_bf16.h>
#include <cstdint>
#include <cstddef>

#define B 4
#define NN 32768
#define NE 262144
#define CV 16
#define CE 16
#define HID 64
#define CM 48   // 2*CV + CE
#define CAP 32  // padded-CSR capacity: degree ~ Binomial(NE,1/NN), mean 8; P(d>=32)~1e-11

using frag  = __attribute__((ext_vector_type(8))) short;
using f32x4 = __attribute__((ext_vector_type(4))) float;

__device__ __forceinline__ float fast_tanh(float x) {
    float e = __expf(2.0f * x);
    return 1.0f - 2.0f / (e + 1.0f);
}

__device__ __forceinline__ unsigned short f2bf(float x) {
    union { float f; unsigned u; } v; v.f = x;
    unsigned r = (v.u + 0x7FFFu + ((v.u >> 16) & 1u)) >> 16;
    return (unsigned short)r;
}

__device__ __forceinline__ float bf2f(unsigned short x) {
    union { unsigned u; float f; } v; v.u = ((unsigned)x) << 16;
    return v.f;
}

__device__ __forceinline__ unsigned pk2bf(float lo, float hi) {
    union { __hip_bfloat162 h; unsigned u; } v;
    v.h = __float22bfloat162_rn(make_float2(lo, hi));
    return v.u;
}

// wave-private swizzled LDS offset: 128 B row stride; XOR byte bits 4..6 with row&7
__device__ __forceinline__ unsigned swo(int row, int byte_off) {
    return (unsigned)((row << 7) + (byte_off ^ ((row & 7) << 4)));
}

__device__ __forceinline__ void acc8(float* a, uint4 v) {
    a[0] += bf2f((unsigned short)(v.x & 0xFFFFu));
    a[1] += bf2f((unsigned short)(v.x >> 16));
    a[2] += bf2f((unsigned short)(v.y & 0xFFFFu));
    a[3] += bf2f((unsigned short)(v.y >> 16));
    a[4] += bf2f((unsigned short)(v.z & 0xFFFFu));
    a[5] += bf2f((unsigned short)(v.z >> 16));
    a[6] += bf2f((unsigned short)(v.w & 0xFFFFu));
    a[7] += bf2f((unsigned short)(v.w >> 16));
}

// ------- fused count + padded-CSR index + weight prepack + bf16 node table ------------
// Padded CSR (row = CAP ints = 128 B = one cache line per node) removes the prefix scan
// and the rank round-trip: r = atomicAdd(cnt[n]); eidx[n*CAP+r] = e. One kernel replaces
// the count -> scan -> eidx three-launch chain.
__global__ __launch_bounds__(256) void countidx_kernel(
    const int* __restrict__ ca, const int* __restrict__ cb,
    int* __restrict__ cnt_a, int* __restrict__ cnt_b,
    int* __restrict__ eidx_a, int* __restrict__ eidx_b,
    const float* __restrict__ Wm1, const float* __restrict__ bm1,
    const float* __restrict__ Wm2,
    const float* __restrict__ Wu1, const float* __restrict__ bu1,
    const float* __restrict__ Wu2,
    const float* __restrict__ node_vals,
    unsigned short* __restrict__ pW1, unsigned short* __restrict__ pW2,
    unsigned short* __restrict__ pWu1, unsigned short* __restrict__ pWu2,
    unsigned short* __restrict__ nv16)
{
    int e = blockIdx.x * 256 + threadIdx.x;
    int na = ca[e], nb = cb[e];
    int ra = atomicAdd(&cnt_a[na], 1);
    eidx_a[na * CAP + ra] = e;
    int rb = atomicAdd(&cnt_b[nb], 1);
    eidx_b[nb * CAP + rb] = e;

    {
        int x0 = e * 8;
        const float4* src = (const float4*)(node_vals + x0);
        float4 v0 = src[0], v1 = src[1];
        uint4 o;
        o.x = pk2bf(v0.x, v0.y); o.y = pk2bf(v0.z, v0.w);
        o.z = pk2bf(v1.x, v1.y); o.w = pk2bf(v1.z, v1.w);
        *(uint4*)(nv16 + x0) = o;
    }

    if (blockIdx.x == 0) {
        for (int x = threadIdx.x; x < 4 * 2 * 64 * 8; x += 256) {
            int j = x & 7, lane = (x >> 3) & 63, ks = (x >> 9) & 1, mt = x >> 10;
            int m = mt * 16 + (lane & 15);
            int k = ks * 32 + (lane >> 4) * 8 + j;
            float w = (k < 48) ? Wm1[k * 64 + m] : (k == 48 ? bm1[m] : 0.0f);
            pW1[x] = f2bf(w);
        }
    } else if (blockIdx.x == 1) {
        for (int x = threadIdx.x; x < 3 * 2 * 64 * 8; x += 256) {
            int j = x & 7, lane = (x >> 3) & 63, ks = (x >> 9) & 1, mt = x >> 10;
            int m = mt * 16 + (lane & 15);
            int k = ks * 32 + (lane >> 4) * 8 + j;
            pW2[x] = f2bf(Wm2[k * 48 + m]);
        }
    } else if (blockIdx.x == 2) {
        for (int x = threadIdx.x; x < 4 * 2 * 64 * 8; x += 256) {
            int j = x & 7, lane = (x >> 3) & 63, ks = (x >> 9) & 1, mt = x >> 10;
            int m = mt * 16 + (lane & 15);
            int k = ks * 32 + (lane >> 4) * 8 + j;
            float w = (k < 48) ? Wu1[k * 64 + m] : (k == 48 ? bu1[m] : 0.0f);
            pWu1[x] = f2bf(w);
        }
    } else if (blockIdx.x == 3) {
        for (int x = threadIdx.x; x < 2 * 64 * 8; x += 256) {
            int j = x & 7, lane = (x >> 3) & 63, ks = x >> 9;
            int m = lane & 15;
            int k = ks * 32 + (lane >> 4) * 8 + j;
            pWu2[x] = f2bf(Wu2[k * 16 + m]);
        }
    }
}

// ---------------- edge MLP via bf16 MFMA (exact R10 version: proven 80 us) ------------
__global__ __launch_bounds__(256, 5) void edge_kernel(
    const unsigned short* __restrict__ nv16, const float* __restrict__ edge_vals,
    const int* __restrict__ ca, const int* __restrict__ cb,
    const unsigned short* __restrict__ pW1, const unsigned short* __restrict__ pW2,
    const float* __restrict__ bm2,
    float* __restrict__ out_edge,
    unsigned short* __restrict__ ma, unsigned short* __restrict__ mb)
{
    __shared__ unsigned short sH[256 * 64];   // 32768 B
    char* sB = (char*)sH;

    int t    = threadIdx.x;
    int lane = t & 63;
    int col  = lane & 15;
    int quad = lane >> 4;
    int erow = (t >> 6) * 64;
    int cha  = quad * 4;

    size_t eb  = (size_t)blockIdx.x * 256;
    size_t idx = eb + t;
    int e  = (int)(idx & (NE - 1));
    int bb = (int)(idx >> 18);

    int na = ca[e], nb = cb[e];

    {
        const uint4* gA = (const uint4*)(nv16 + ((size_t)bb * NN + na) * CV);
        const uint4* gB = (const uint4*)(nv16 + ((size_t)bb * NN + nb) * CV);
        uint4 a0 = gA[0], a1 = gA[1];
        uint4 b0 = gB[0], b1 = gB[1];
        const float4* pE = (const float4*)(edge_vals + idx * CE);
        float4 ev0 = pE[0], ev1 = pE[1], ev2 = pE[2], ev3 = pE[3];

        unsigned pk[32];
        *(uint4*)&pk[0]  = a0;  *(uint4*)&pk[4]  = a1;
        *(uint4*)&pk[8]  = b0;  *(uint4*)&pk[12] = b1;
        pk[16] = pk2bf(ev0.x, ev0.y); pk[17] = pk2bf(ev0.z, ev0.w);
        pk[18] = pk2bf(ev1.x, ev1.y); pk[19] = pk2bf(ev1.z, ev1.w);
        pk[20] = pk2bf(ev2.x, ev2.y); pk[21] = pk2bf(ev2.z, ev2.w);
        pk[22] = pk2bf(ev3.x, ev3.y); pk[23] = pk2bf(ev3.z, ev3.w);
        pk[24] = 0x3F80u;   // bias row: h[48] = 1.0
#pragma unroll
        for (int q = 25; q < 32; q++) pk[q] = 0;
        const uint4* src = (const uint4*)pk;
#pragma unroll
        for (int q = 0; q < 8; q++)
            *(uint4*)(sB + swo(t, q * 16)) = src[q];
    }
    asm volatile("s_waitcnt lgkmcnt(0)" ::: "memory");   // (1) own-wave h rows visible

#pragma unroll
    for (int hh = 0; hh < 2; hh++) {
        int r0 = erow + hh * 32 + col;

        frag w1f[4][2];
#pragma unroll
        for (int mt = 0; mt < 4; mt++)
#pragma unroll
            for (int ks = 0; ks < 2; ks++)
                w1f[mt][ks] = *(const frag*)&pW1[(((mt * 2 + ks) * 64) + lane) * 8];

        f32x4 acc1[4][2];
#pragma unroll
        for (int mt = 0; mt < 4; mt++)
#pragma unroll
            for (int n = 0; n < 2; n++) acc1[mt][n] = (f32x4){0.f, 0.f, 0.f, 0.f};

#pragma unroll
        for (int ks = 0; ks < 2; ks++) {
            frag bfr[2];
#pragma unroll
            for (int n = 0; n < 2; n++)
                bfr[n] = *(const frag*)(sB + swo(r0 + n * 16, ks * 64 + quad * 16));
#pragma unroll
            for (int mt = 0; mt < 4; mt++)
#pragma unroll
                for (int n = 0; n < 2; n++)
                    acc1[mt][n] = __builtin_amdgcn_mfma_f32_16x16x32_bf16(
                        w1f[mt][ks], bfr[n], acc1[mt][n], 0, 0, 0);
        }

#pragma unroll
        for (int n = 0; n < 2; n++) {
            int row = r0 + n * 16;
#pragma unroll
            for (int mt = 0; mt < 4; mt++) {
                uint2 w;
                w.x = pk2bf(fast_tanh(acc1[mt][n][0]), fast_tanh(acc1[mt][n][1]));
                w.y = pk2bf(fast_tanh(acc1[mt][n][2]), fast_tanh(acc1[mt][n][3]));
                *(uint2*)(sB + swo(row, mt * 32 + quad * 8)) = w;
            }
        }
        asm volatile("s_waitcnt lgkmcnt(0)" ::: "memory");  // (2) T rows of this half visible

        frag w2f[3][2];
#pragma unroll
        for (int mt = 0; mt < 3; mt++)
#pragma unroll
            for (int ks = 0; ks < 2; ks++)
                w2f[mt][ks] = *(const frag*)&pW2[(((mt * 2 + ks) * 64) + lane) * 8];

        f32x4 acc2[3][2];
#pragma unroll
        for (int mt = 0; mt < 3; mt++)
#pragma unroll
            for (int n = 0; n < 2; n++) acc2[mt][n] = (f32x4){0.f, 0.f, 0.f, 0.f};

#pragma unroll
        for (int ks = 0; ks < 2; ks++) {
            frag bfr[2];
#pragma unroll
            for (int n = 0; n < 2; n++)
                bfr[n] = *(const frag*)(sB + swo(r0 + n * 16, ks * 64 + quad * 16));
#pragma unroll
            for (int mt = 0; mt < 3; mt++)
#pragma unroll
                for (int n = 0; n < 2; n++)
                    acc2[mt][n] = __builtin_amdgcn_mfma_f32_16x16x32_bf16(
                        w2f[mt][ks], bfr[n], acc2[mt][n], 0, 0, 0);
        }

        // out_edge in-loop from acc2 (+ L2-hot re-read of this block's edge_vals range)
        float4 b2e = *(const float4*)&bm2[32 + cha];
#pragma unroll
        for (int n = 0; n < 2; n++) {
            int le = r0 + n * 16;
            size_t o = (eb + le) * CE + cha;
            float4 evv = *(const float4*)&edge_vals[o];
            float4 ov;
            ov.x = evv.x + acc2[2][n][0] + b2e.x;
            ov.y = evv.y + acc2[2][n][1] + b2e.y;
            ov.z = evv.z + acc2[2][n][2] + b2e.z;
            ov.w = evv.w + acc2[2][n][3] + b2e.w;
            *(float4*)&out_edge[o] = ov;
        }

        float4 b2a = *(const float4*)&bm2[cha];
        float4 b2b = *(const float4*)&bm2[16 + cha];
#pragma unroll
        for (int n = 0; n < 2; n++) {
            int row = r0 + n * 16;
            uint2 wa;
            wa.x = pk2bf(acc2[0][n][0] + b2a.x, acc2[0][n][1] + b2a.y);
            wa.y = pk2bf(acc2[0][n][2] + b2a.z, acc2[0][n][3] + b2a.w);
            *(uint2*)(sB + swo(row, quad * 8)) = wa;
            uint2 wb;
            wb.x = pk2bf(acc2[1][n][0] + b2b.x, acc2[1][n][1] + b2b.y);
            wb.y = pk2bf(acc2[1][n][2] + b2b.z, acc2[1][n][3] + b2b.w);
            *(uint2*)(sB + swo(row, 32 + quad * 8)) = wb;
        }
    }
    asm volatile("s_waitcnt lgkmcnt(0)" ::: "memory");   // (3) all m rows visible

    {
        uint4 a0 = *(const uint4*)(sB + swo(t, 0));
        uint4 a1 = *(const uint4*)(sB + swo(t, 16));
        uint4 b0 = *(const uint4*)(sB + swo(t, 32));
        uint4 b1 = *(const uint4*)(sB + swo(t, 48));
        unsigned short* pa = &ma[idx * 16];
        *(uint4*)(pa + 0) = a0;
        *(uint4*)(pa + 8) = a1;
        unsigned short* pb = &mb[idx * 16];
        *(uint4*)(pb + 0) = b0;
        *(uint4*)(pb + 8) = b1;
    }
}

// ---------------- fused gather-mean aggregation + node MLP (R10 node, padded CSR) -----
__global__ __launch_bounds__(512) void node_kernel(
    const float* __restrict__ node_vals,
    const unsigned short* __restrict__ ma, const unsigned short* __restrict__ mb,
    const int* __restrict__ eidx_a, const int* __restrict__ eidx_b,
    const int* __restrict__ cnt_a, const int* __restrict__ cnt_b,
    const unsigned short* __restrict__ pWu1, const unsigned short* __restrict__ pWu2,
    const float* __restrict__ bu2,
    float* __restrict__ out_node)
{
    __shared__ unsigned short sH[256 * 64];   // 32768 B
    char* sB = (char*)sH;

    int t    = threadIdx.x;      // 0..511
    int tn   = t & 255;          // node slot within block
    int half = t >> 8;           // 0 = a-stream, 1 = b-stream
    int g = blockIdx.x * 256 + tn;
    int n = g & (NN - 1);
    int b = g >> 15;

    float4 pn[4];   // valid for half==0 threads

    {
        const int* cntp = half ? cnt_b : cnt_a;
        const int* ep   = half ? eidx_b : eidx_a;
        const unsigned short* mp = (half ? mb : ma) + (size_t)b * NE * 16;

        int d = cntp[n];
        const int* ix = ep + n * CAP;   // padded row: 128 B, one line

        float u[16] = {0.f,0.f,0.f,0.f,0.f,0.f,0.f,0.f,0.f,0.f,0.f,0.f,0.f,0.f,0.f,0.f};
        for (int k0 = 0; k0 < d; k0 += 4) {
            uint4 v[4][2];
            int nn_ = d - k0; nn_ = (nn_ > 4) ? 4 : nn_;
#pragma unroll
            for (int j = 0; j < 4; j++) {
                if (j < nn_) {
                    int ee = ix[k0 + j];
                    const uint4* p = (const uint4*)(mp + (size_t)ee * 16);
                    v[j][0] = p[0]; v[j][1] = p[1];
                }
            }
#pragma unroll
            for (int j = 0; j < 4; j++) {
                if (j < nn_) { acc8(&u[0], v[j][0]); acc8(&u[8], v[j][1]); }
            }
        }
        float inv = 1.0f / (float)max(d, 1);
        unsigned pk[8];
#pragma unroll
        for (int q = 0; q < 8; q++) pk[q] = pk2bf(u[2*q] * inv, u[2*q+1] * inv);
        *(uint4*)(sB + swo(tn, half * 32 + 0))  = ((const uint4*)pk)[0];
        *(uint4*)(sB + swo(tn, half * 32 + 16)) = ((const uint4*)pk)[1];

        if (half == 0) {
            const float4* pnv = (const float4*)(node_vals + (size_t)g * CV);
#pragma unroll
            for (int q = 0; q < 4; q++) pn[q] = pnv[q];
            unsigned pk2[16];
#pragma unroll
            for (int q = 0; q < 4; q++) {
                pk2[2*q + 0] = pk2bf(pn[q].x, pn[q].y);
                pk2[2*q + 1] = pk2bf(pn[q].z, pn[q].w);
            }
            pk2[8] = 0x3F80u;   // bias row: u[48] = 1.0 (bu1 folded into pWu1 row 48)
#pragma unroll
            for (int q = 9; q < 16; q++) pk2[q] = 0;
#pragma unroll
            for (int q = 0; q < 4; q++)
                *(uint4*)(sB + swo(tn, 64 + q * 16)) = ((const uint4*)pk2)[q];
        }
    }
    __syncthreads();   // (1) all u rows complete (cross-wave)

    // ---- MFMA phase: wave wv -> band wv&3, half hh = wv>>2 ----
    {
        int lane = t & 63;
        int col  = lane & 15;
        int quad = lane >> 4;
        int wv   = t >> 6;
        int band = wv & 3;
        int hh   = wv >> 2;
        int r0 = band * 64 + hh * 32 + col;

        frag w1f[4][2];
#pragma unroll
        for (int mt = 0; mt < 4; mt++)
#pragma unroll
            for (int ks = 0; ks < 2; ks++)
                w1f[mt][ks] = *(const frag*)&pWu1[(((mt * 2 + ks) * 64) + lane) * 8];

        f32x4 acc1[4][2];
#pragma unroll
        for (int mt = 0; mt < 4; mt++)
#pragma unroll
            for (int nt = 0; nt < 2; nt++) acc1[mt][nt] = (f32x4){0.f, 0.f, 0.f, 0.f};

#pragma unroll
        for (int ks = 0; ks < 2; ks++) {
            frag bfr[2];
#pragma unroll
            for (int nt = 0; nt < 2; nt++)
                bfr[nt] = *(const frag*)(sB + swo(r0 + nt * 16, ks * 64 + quad * 16));
#pragma unroll
            for (int mt = 0; mt < 4; mt++)
#pragma unroll
                for (int nt = 0; nt < 2; nt++)
                    acc1[mt][nt] = __builtin_amdgcn_mfma_f32_16x16x32_bf16(
                        w1f[mt][ks], bfr[nt], acc1[mt][nt], 0, 0, 0);
        }

#pragma unroll
        for (int nt = 0; nt < 2; nt++) {
            int row = r0 + nt * 16;
#pragma unroll
            for (int mt = 0; mt < 4; mt++) {
                uint2 w;
                w.x = pk2bf(fast_tanh(acc1[mt][nt][0]), fast_tanh(acc1[mt][nt][1]));
                w.y = pk2bf(fast_tanh(acc1[mt][nt][2]), fast_tanh(acc1[mt][nt][3]));
                *(uint2*)(sB + swo(row, mt * 32 + quad * 8)) = w;
            }
        }
        asm volatile("s_waitcnt lgkmcnt(0)" ::: "memory");   // T rows (wave-local)

        frag w2f[2];
#pragma unroll
        for (int ks = 0; ks < 2; ks++)
            w2f[ks] = *(const frag*)&pWu2[(ks * 64 + lane) * 8];

        f32x4 acc2[2];
#pragma unroll
        for (int nt = 0; nt < 2; nt++) acc2[nt] = (f32x4){0.f, 0.f, 0.f, 0.f};

#pragma unroll
        for (int ks = 0; ks < 2; ks++) {
            frag bfr[2];
#pragma unroll
            for (int nt = 0; nt < 2; nt++)
                bfr[nt] = *(const frag*)(sB + swo(r0 + nt * 16, ks * 64 + quad * 16));
#pragma unroll
            for (int nt = 0; nt < 2; nt++)
                acc2[nt] = __builtin_amdgcn_mfma_f32_16x16x32_bf16(
                    w2f[ks], bfr[nt], acc2[nt], 0, 0, 0);
        }

#pragma unroll
        for (int nt = 0; nt < 2; nt++) {
            int row = r0 + nt * 16;
            float4 v;
            v.x = acc2[nt][0]; v.y = acc2[nt][1];
            v.z = acc2[nt][2]; v.w = acc2[nt][3];
            *(float4*)(sB + swo(row, 64 + quad * 16)) = v;
        }
    }
    __syncthreads();   // (2) all update rows complete (cross-wave)

    if (half == 0) {
        const float4* pb2 = (const float4*)bu2;
        float4* po = (float4*)&out_node[(size_t)g * CV];
#pragma unroll
        for (int q = 0; q < 4; q++) {
            float4 m = *(const float4*)(sB + swo(tn, 64 + q * 16));
            float4 c = pb2[q];
            float4 o;
            o.x = pn[q].x + m.x + c.x;
            o.y = pn[q].y + m.y + c.y;
            o.z = pn[q].z + m.z + c.z;
            o.w = pn[q].w + m.w + c.w;
            po[q] = o;
        }
    }
}

extern "C" void kernel_launch(void* const* d_in, const int* in_sizes, int n_in,
                              void* d_out, int out_size, void* d_ws, size_t ws_size,
                              hipStream_t stream) {
    const float* node_vals = (const float*)d_in[0];
    const float* edge_vals = (const float*)d_in[1];
    const int*   ca        = (const int*)d_in[2];
    const int*   cb        = (const int*)d_in[3];
    const float* Wm1 = (const float*)d_in[4];
    const float* bm1 = (const float*)d_in[5];
    const float* Wm2 = (const float*)d_in[6];
    const float* bm2 = (const float*)d_in[7];
    const float* Wu1 = (const float*)d_in[8];
    const float* bu1 = (const float*)d_in[9];
    const float* Wu2 = (const float*)d_in[10];
    const float* bu2 = (const float*)d_in[11];

    float* out_node = (float*)d_out;
    float* out_edge = out_node + (size_t)B * NN * CV;

    unsigned short* ma = (unsigned short*)d_ws;                   // B*NE*16 bf16 (32 MB)
    unsigned short* mb = ma + (size_t)B * NE * 16;                // 32 MB
    int* cnt_a   = (int*)(mb + (size_t)B * NE * 16);
    int* cnt_b   = cnt_a + NN;
    int* eidx_a  = cnt_b + NN;                                    // NN*CAP ints (4 MB)
    int* eidx_b  = eidx_a + NN * CAP;                             // 4 MB
    unsigned short* pW1  = (unsigned short*)(eidx_b + NN * CAP);  // 4096 bf16
    unsigned short* pW2  = pW1 + 4096;                            // 3072 bf16
    unsigned short* pWu1 = pW2 + 3072;                            // 4096 bf16
    unsigned short* pWu2 = pWu1 + 4096;                           // 1024 bf16
    unsigned short* nv16 = pWu2 + 1024;                           // B*NN*CV bf16 (4 MB)

    hipMemsetAsync(cnt_a, 0, 2 * (size_t)NN * sizeof(int), stream);

    countidx_kernel<<<NE / 256, 256, 0, stream>>>(
        ca, cb, cnt_a, cnt_b, eidx_a, eidx_b,
        Wm1, bm1, Wm2, Wu1, bu1, Wu2, node_vals,
        pW1, pW2, pWu1, pWu2, nv16);
    edge_kernel<<<(B * NE) / 256, 256, 0, stream>>>(
        nv16, edge_vals, ca, cb, pW1, pW2, bm2, out_edge, ma, mb);
    node_kernel<<<(B * NN) / 256, 512, 0, stream>>>(
        node_vals, ma, mb, eidx_a, eidx_b, cnt_a, cnt_b,
        pWu1, pWu2, bu2, out_node);
}